// Round 1
// baseline (22.161 us; speedup 1.0000x reference)
//
#include <hip/hip_runtime.h>

// Problem constants (from reference):
//   x: (PH*PW=49, B=2, C=3, 256, 256) fp32
//   out: (2, 3, 1024, 1024) fp32
//   out[b,c,h,w] = max over patches (i,j) with i*128<=h<i*128+256,
//                  j*128<=w<j*128+256 of x[i*7+j, b, c, h-i*128, w-j*128]
#define PATCH   256
#define STRIDEP 128
#define Bn      2
#define Cn      3
#define Hn      1024
#define Wn      1024
#define PHn     7
#define PWn     7

__global__ __launch_bounds__(256) void unpatch_max_kernel(
    const float* __restrict__ x, float* __restrict__ out)
{
    // One thread per float4 of output. Total float4s: 2*3*1024*1024/4 = 1572864.
    const int gid = blockIdx.x * blockDim.x + threadIdx.x;
    const int W4  = Wn / 4;                 // 256 float4 per row
    // decompose gid -> (bc, h, w4)
    const int w4   = gid & (W4 - 1);        // W4=256 -> pow2
    const int rest = gid >> 8;              // gid / 256
    const int h    = rest & (Hn - 1);       // Hn=1024 -> pow2
    const int bc   = rest >> 10;            // b*Cn + c, in [0,6)
    const int w    = w4 << 2;

    // covering patch rows/cols: {floor(h/128)-1, floor(h/128)} clamped to [0,6]
    const int hi = h >> 7;
    const int i1 = hi < PHn ? hi : (PHn - 1);
    const int i0 = hi > 0 ? hi - 1 : 0;
    const int wi = w >> 7;
    const int j1 = wi < PWn ? wi : (PWn - 1);
    const int j0 = wi > 0 ? wi - 1 : 0;

    float4 m = make_float4(-INFINITY, -INFINITY, -INFINITY, -INFINITY);

    #pragma unroll 2
    for (int i = i0; i <= i1; ++i) {
        const int ph = h - i * STRIDEP;     // in [0,256)
        #pragma unroll 2
        for (int j = j0; j <= j1; ++j) {
            const int pw  = w - j * STRIDEP;             // in [0,256), 4-aligned
            const int idx = i * PWn + j;                 // patch index
            const size_t off =
                ((size_t)(idx * (Bn * Cn) + bc) * PATCH + ph) * PATCH + pw;
            const float4 v = *reinterpret_cast<const float4*>(x + off);
            m.x = fmaxf(m.x, v.x);
            m.y = fmaxf(m.y, v.y);
            m.z = fmaxf(m.z, v.z);
            m.w = fmaxf(m.w, v.w);
        }
    }

    *reinterpret_cast<float4*>(out + (size_t)gid * 4) = m;
}

extern "C" void kernel_launch(void* const* d_in, const int* in_sizes, int n_in,
                              void* d_out, int out_size, void* d_ws, size_t ws_size,
                              hipStream_t stream)
{
    const float* x = (const float*)d_in[0];
    float* out = (float*)d_out;

    const int total4 = (Bn * Cn * Hn * Wn) / 4;   // 1572864
    const int block  = 256;
    const int grid   = total4 / block;            // 6144
    unpatch_max_kernel<<<grid, block, 0, stream>>>(x, out);
}